// Round 4
// baseline (115.289 us; speedup 1.0000x reference)
//
#include <hip/hip_runtime.h>

#define BATCH  8
#define CH     64
#define H      128
#define W      128
#define TH     4                   // tile rows per block (full-width tiles)
#define CHUNK  8                   // channels per block
#define NCHUNK (CH / CHUNK)        // 8
#define HWID   (W + 2)             // 130
#define HHGT   (TH + 2)            // 6
#define HALO_N (HWID * HHGT)       // 780
#define NSLOT  4                   // ceil(780/256)
#define HW     (H * W)             // 16384

typedef float vfloat4 __attribute__((ext_vector_type(4)));  // clang vector — valid for nontemporal builtins

__device__ __forceinline__ float sigmoidf_(float v) {
    return 1.0f / (1.0f + __expf(-v));
}

// Kernel 1: each block computes the sum over its 8-channel chunk for a 128x4
// pixel tile, writes the partial (non-atomic, exclusive) into
// ws[b][chunk][h][w]. Double-buffered LDS halo: ONE barrier per channel.
__global__ __launch_bounds__(256) void partial_kernel(
    const float* __restrict__ x,
    const float* __restrict__ weight,
    const float* __restrict__ bias,
    const float* __restrict__ wcp,
    const float* __restrict__ wmp,
    float* __restrict__ ws)
{
    __shared__ float sm[2][HALO_N];

    const int tid  = threadIdx.x;
    const int tx   = tid & (W - 1);          // 0..127
    const int ty0  = (tid >> 7) * 2;         // 0 or 2 (each thread: 2 rows)
    const int by   = blockIdx.x;             // H/TH = 32
    const int chnk = blockIdx.y;             // NCHUNK = 8
    const int b    = blockIdx.z;             // BATCH

    // ---- channel-invariant halo-slot geometry ----
    bool has[NSLOT], ok[NSLOT];
    int  off[NSLOT];
    #pragma unroll
    for (int s = 0; s < NSLOT; ++s) {
        int i  = tid + s * 256;
        has[s] = (i < HALO_N);
        int ic = has[s] ? i : (HALO_N - 1);
        int yy = ic / HWID;
        int xx = ic - yy * HWID;
        int sy = by * TH + yy - 1;
        int sx = xx - 1;
        ok[s]  = (sy >= 0 && sy < H && sx >= 0 && sx < W);
        off[s] = min(max(sy, 0), H - 1) * W + min(max(sx, 0), W - 1);
    }

    // ---- per-k constants (broadcast scalar loads) ----
    float wk[9], bk[9];
    #pragma unroll
    for (int k = 0; k < 9; ++k) {
        wk[k] = sigmoidf_(weight[k]);
        bk[k] = sigmoidf_(bias[k]);
    }
    const float wc = wcp[0];
    const float wm = wmp[0];

    const float* xb = x + ((size_t)b * CH + chnk * CHUNK) * HW;

    // stage channel 0
    float r[NSLOT];
    #pragma unroll
    for (int s = 0; s < NSLOT; ++s) r[s] = xb[off[s]];
    #pragma unroll
    for (int s = 0; s < NSLOT; ++s)
        if (has[s]) sm[0][tid + s * 256] = ok[s] ? sigmoidf_(r[s]) : 0.0f;
    __syncthreads();

    float acc0 = 0.0f, acc1 = 0.0f;

    for (int c = 0; c < CHUNK; ++c) {
        const int cur = c & 1;

        // issue next channel's loads; consumed after this channel's compute
        if (c + 1 < CHUNK) {
            const float* xn = xb + (size_t)(c + 1) * HW;
            #pragma unroll
            for (int s = 0; s < NSLOT; ++s) r[s] = xn[off[s]];
        }

        // 4 rows x 3 cols window shared by this thread's two pixels
        float v[4][3];
        #pragma unroll
        for (int dy = 0; dy < 4; ++dy)
            #pragma unroll
            for (int dx = 0; dx < 3; ++dx)
                v[dy][dx] = sm[cur][(ty0 + dy) * HWID + tx + dx];

        #pragma unroll
        for (int j = 0; j < 2; ++j) {
            float d[9];
            float sum = 0.0f;
            #pragma unroll
            for (int dy = 0; dy < 3; ++dy)
                #pragma unroll
                for (int dx = 0; dx < 3; ++dx) {
                    int k = dy * 3 + dx;
                    float dk = fmaxf(wk[k], v[j + dy][dx]) + bk[k];
                    d[k] = dk;
                    sum += dk;
                }
            const float center = v[j + 1][1];

            // median-of-9 (McGuire ShaderX6 network)
            #define S2(a,bb) { float t = d[a]; d[a] = fminf(d[a], d[bb]); d[bb] = fmaxf(t, d[bb]); }
            S2(0,3) S2(1,4) S2(2,5) S2(0,1) S2(0,2) S2(4,5) S2(3,5)
            S2(1,2) S2(3,4) S2(1,3) S2(1,6) S2(4,6) S2(2,6)
            S2(2,3) S2(4,7) S2(2,4) S2(3,7)
            S2(4,8) S2(3,8) S2(3,4)
            #undef S2
            const float med = d[4];

            const float r_ = wc * center + wm * med - sum - sum * (1.0f / 9.0f);
            if (j == 0) acc0 += r_; else acc1 += r_;
        }

        // stage next channel into the other buffer; single barrier per iter
        if (c + 1 < CHUNK) {
            #pragma unroll
            for (int s = 0; s < NSLOT; ++s)
                if (has[s]) sm[cur ^ 1][tid + s * 256] = ok[s] ? sigmoidf_(r[s]) : 0.0f;
        }
        __syncthreads();
    }

    float* op = ws + ((size_t)b * NCHUNK + chnk) * HW
                   + (size_t)(by * TH + ty0) * W + tx;
    op[0] = acc0;
    op[W] = acc1;
}

// Kernel 2: per pixel, sum the 8 partial planes (ws) and broadcast to 16 of
// the 64 output planes (blockIdx.y picks the 16-plane group). dwordx4
// everywhere; nontemporal stores keep the 33.5 MB out-stream out of L2.
__global__ __launch_bounds__(256) void broadcast_kernel(
    const float* __restrict__ ws,
    float* __restrict__ out)
{
    const int g  = (blockIdx.x * 256 + threadIdx.x) * 4;  // pixel base
    const int b  = g >> 14;                                // HW = 16384
    const int p  = g & (HW - 1);
    const int c0 = blockIdx.y * 16;

    const float* wsb = ws + (size_t)b * NCHUNK * HW + p;
    vfloat4 s = (vfloat4)(0.0f);
    #pragma unroll
    for (int k = 0; k < NCHUNK; ++k) {
        vfloat4 v = *(const vfloat4*)(wsb + (size_t)k * HW);
        s += v;
    }

    float* base = out + ((size_t)b * CH + c0) * HW + p;
    #pragma unroll
    for (int j = 0; j < 16; ++j)
        __builtin_nontemporal_store(s, (vfloat4*)(base + (size_t)j * HW));
}

extern "C" void kernel_launch(void* const* d_in, const int* in_sizes, int n_in,
                              void* d_out, int out_size, void* d_ws, size_t ws_size,
                              hipStream_t stream) {
    const float* x      = (const float*)d_in[0];
    const float* weight = (const float*)d_in[1];
    const float* bias   = (const float*)d_in[2];
    const float* wcp    = (const float*)d_in[3];
    const float* wmp    = (const float*)d_in[4];
    float* out = (float*)d_out;
    float* ws  = (float*)d_ws;      // 8*8*16384*4 B = 4 MiB used

    dim3 grid1(H / TH, NCHUNK, BATCH);            // 32 x 8 x 8 = 2048 blocks
    partial_kernel<<<grid1, 256, 0, stream>>>(x, weight, bias, wcp, wmp, ws);

    dim3 grid2(BATCH * HW / (4 * 256), CH / 16);  // 128 x 4 = 512 blocks
    broadcast_kernel<<<grid2, 256, 0, stream>>>(ws, out);
}